// Round 15
// baseline (2318.570 us; speedup 1.0000x reference)
//
#include <hip/hip_runtime.h>

// Problem constants
#define Tt 256

// ws layout in unsigned shorts (fp16 bit patterns / ints for flags):
//  flags : ints [0..256) global arrival flags (4B packed)
//  h0 [2 parity][64 g][128 row][8]  fp16 frag-major     (g = col>>3)
//  h1 same
//  aux  : ints at AUXOFF — [0..8) per-XCD rank tickets, [8..8+256) intra-XCD flags
//  staged : per-XCD copy of the current-parity h0+h1 planes (2 x 64Ku16 per XCD)
#define FLAGS_SHORTS 16384
#define H0OFF  16384
#define H1OFF  (H0OFF + 2*64*128*8)
#define HPAR   (64*128*8)            // u16 per parity plane = 65536
#define AUXOFF (H1OFF + 2*64*128*8)  // = 278528 (old wlo region, now free)
#define STGOFF (AUXOFF + 4096)       // staging: 8 xcd x 2 planes x HPAR u16 = 2 MB

typedef _Float16 h8 __attribute__((ext_vector_type(8)));
typedef float    f4 __attribute__((ext_vector_type(4)));
typedef unsigned long long ull;
typedef unsigned short u16;

#define MFMA __builtin_amdgcn_mfma_f32_16x16x32_f16
#define LOSC (1.0f/1024.0f)

__device__ inline u16 h_bits(float f){ union{_Float16 h; u16 s;} u; u.h=(_Float16)f; return u.s; }
__device__ inline float bits_f(u16 s){ union{u16 s2; _Float16 h;} u; u.s2=s; return (float)u.h; }
__device__ inline float sigm(float x){ return 1.f/(1.f+expf(-x)); }

// ---- R14 (proven): single-transaction 16B coherent load (SC0|SC1, MALL-served) ----
__device__ inline __amdgpu_buffer_rsrc_t make_rsrc(const void* base){
    return __builtin_amdgcn_make_buffer_rsrc((void*)base, /*stride*/(short)0,
                                             /*num_records*/0xFFFFFFFFu,
                                             /*flags word3*/0x00020000);
}
__device__ inline h8 ldH(__amdgpu_buffer_rsrc_t rsrc, int u16idx){
    auto d = __builtin_amdgcn_raw_buffer_load_b128(rsrc, u16idx * 2, 0, 17 /*SC0|SC1*/);
    h8 v; __builtin_memcpy(&v, &d, 16);
    return v;
}
// R21: intra-XCD consumer load — SC0 (GLC) only: bypass L1, HIT the XCD-local L2
// where the staging copy was just written by same-XCD blocks.
__device__ inline h8 ldG(__amdgpu_buffer_rsrc_t rsrc, int u16idx){
    auto d = __builtin_amdgcn_raw_buffer_load_b128(rsrc, u16idx * 2, 0, 1 /*SC0*/);
    h8 v; __builtin_memcpy(&v, &d, 16);
    return v;
}

// Fence-free global split barrier — proven structure (threads 0..255 poll packed flags).
__device__ inline void barrier_arrive(int* __restrict__ flags, int tid, int bid, int target) {
    __builtin_amdgcn_s_waitcnt(0);
    __syncthreads();
    if (tid == 0)
        __hip_atomic_store(flags + bid, target, __ATOMIC_RELAXED, __HIP_MEMORY_SCOPE_AGENT);
}
__device__ inline void barrier_wait(int* __restrict__ flags, int tid, int target) {
    if (tid < 256)
        while (__hip_atomic_load(flags + tid, __ATOMIC_RELAXED, __HIP_MEMORY_SCOPE_AGENT) < target)
            __builtin_amdgcn_s_sleep(4);
    __syncthreads();
}

struct X4 { f4 h0, l0, h1, l1; };

// ---------------- persistent cooperative LSTM kernel ----------------
// grid 256 x 1024 (1 block/CU, 16 waves): R8-proven geometry, R20-proven wlo-in-LDS.
// R21 change (single structural variable): PER-XCD h STAGING.
//   The coherent SC0|SC1 h-reads bypass L2, so the 94x-redundant 24 MB/phase
//   broadcast is all MALL-served (~5.5 us of the 6.2 us phase). Instead: the 32
//   blocks of each XCD import the unique 256 KB (h0+h1 current-parity planes)
//   ONCE coherently (2 MB/phase chip-wide), store to an XCD-private staging
//   buffer (plain stores -> own L2), intra-XCD flag barrier, then consume via
//   GLC loads (L1-bypass, L2-hit). Consumer indexing identical; data bit-identical.
//   xcd from s_getreg(HW_REG_XCC_ID) [HW-verified]; rank from an agent-scope
//   ticket atomicAdd (tickets zeroed by all blocks before the pre-loop global
//   barrier, which orders init -> add); intra-XCD barrier mirrors the proven
//   global flag-barrier structure (poison-safe, monotone targets).
__global__ __launch_bounds__(1024, 1) void lstm_coop(
    const int* __restrict__ x, const float* __restrict__ emb,
    const float* __restrict__ W0, const float* __restrict__ b0,
    const float* __restrict__ W1, const float* __restrict__ b1,
    const float* __restrict__ Wd, const float* __restrict__ bd,
    float* __restrict__ out, u16* __restrict__ ws) {

    const int tid  = threadIdx.x;
    const int lane = tid & 63;
    const int wave = tid >> 6;        // 0..15
    const int mt   = wave & 3;        // m-tile (16 rows each)
    const int g4   = wave >> 2;       // k-quarter 0..3
    const int quad = lane >> 4;       // 0..3 : k-chunk of 8 in frags
    const int fm   = lane & 15;       // A: m, B: n, C/D: col
    const int bid  = blockIdx.x;
    const int lyr  = bid & 1;
    const int inner= bid >> 1;
    const int bq   = inner >> 6;
    const int cg   = inner & 63;

    __shared__ u16   whi[128 * 32 * 8];   // 65,536 B (lyr0 uses first 104*32*8)
    __shared__ u16   wlo[128 * 32 * 8];   // 65,536 B lo-plane
    __shared__ float csm[2][64 * 33];     // 16,896 B -> 147,968 B total
    __shared__ int   srank;

    int* flags = (int*)ws;
    int* aux   = (int*)(ws + AUXOFF);
    const __amdgpu_buffer_rsrc_t rsrc = make_rsrc(ws);

    int xcd;
    asm("s_getreg_b32 %0, hwreg(HW_REG_XCC_ID)" : "=s"(xcd));
    xcd &= 7;
    int* xf = aux + 8 + xcd * 32;                        // this XCD's 32 intra flags
    const int stb = STGOFF + xcd * 2 * HPAR;             // staging base (u16 idx)

    // --- fill LDS hi+lo planes of this block's layer & 32 gate columns, layout [kg][n][8] ---
    if (lyr == 0) {
        for (int i = tid; i < 104 * 32 * 8; i += 1024) {
            int kg = i >> 8; int rem = i & 255; int n = rem >> 3; int j = rem & 7;
            int k = kg * 8 + j;
            int col = ((n >> 3) << 9) + (cg << 3) + (n & 7);
            float w = 0.f;
            if (k < 300) w = W0[k * 2048 + col];
            else if (k >= 320) w = W0[(k - 20) * 2048 + col];
            _Float16 wh = (_Float16)w;
            union{_Float16 h; u16 s;} uh; uh.h = wh;
            whi[i] = uh.s;
            wlo[i] = h_bits((w - (float)wh) * 1024.0f);
        }
    } else {
        for (int i = tid; i < 128 * 32 * 8; i += 1024) {
            int kg = i >> 8; int rem = i & 255; int n = rem >> 3; int j = rem & 7;
            int k = kg * 8 + j;
            int col = ((n >> 3) << 9) + (cg << 3) + (n & 7);
            float w = W1[k * 2048 + col];
            _Float16 wh = (_Float16)w;
            union{_Float16 h; u16 s;} uh; uh.h = wh;
            whi[i] = uh.s;
            wlo[i] = h_bits((w - (float)wh) * 1024.0f);
        }
    }

    // --- zero ticket area (all blocks, same value — benign race; ordered before the
    //     rank atomicAdd by the pre-loop global barrier) ---
    if (tid < 8)
        __hip_atomic_store(aux + tid, 0, __ATOMIC_RELAXED, __HIP_MEMORY_SCOPE_AGENT);

    // h addressing (frag-major, unchanged): plane u16 index = cg*1024 + row*8 + c, c in [0,8)
    // --- zero-init own slice: lyr0 -> h0 parity 0 ; lyr1 -> h1 parity 1 (64 rows x 8 cols) ---
    if (tid < 256) {
        int row = bq * 64 + (tid >> 2);
        int c = (tid & 3) << 1;
        unsigned int* pz = (unsigned int*)(ws + (lyr ? H1OFF + 1 * HPAR : H0OFF + 0 * HPAR)
                                           + cg * 1024 + row * 8 + c);
        __hip_atomic_store(pz, 0u, __ATOMIC_RELAXED, __HIP_MEMORY_SCOPE_AGENT);
    }

    const int arow = bq * 64 + mt * 16 + fm;   // A-frag row (batch index)
    // act cell: ONE cell per thread for tid<512: (row actm 0..63, h-col acthc 0..7)
    const int actm   = tid >> 3;
    const int acthc  = tid & 7;
    const int actrow = bq * 64 + actm;
    const int ca = (cg << 3) + acthc;          // global h-col of the cell

    const float bi = lyr ? b1[ca]        : b0[ca];
    const float bj = lyr ? b1[512 + ca]  : b0[512 + ca];
    const float bf = lyr ? b1[1024 + ca] : b0[1024 + ca];
    const float bo = lyr ? b1[1536 + ca] : b0[1536 + ca];

    float cs = 0.f;

    // x-part GEMM of layer 0 for timestep pp; this wave's k-quarter: kt = ktl*4 + g4 (kt<10).
    auto xgemm = [&](int pp) -> X4 {
        X4 a; a.h0 = (f4){0,0,0,0}; a.l0 = a.h0; a.h1 = a.h0; a.l1 = a.h0;
        int xi = x[arow * Tt + pp];
        xi = (xi < 0) ? 0 : ((xi >= 50000) ? 49999 : xi);
        const float* embrow = emb + (size_t)xi * 300;
#pragma unroll
        for (int ktl = 0; ktl < 3; ktl++) {
            int kt = ktl * 4 + g4;
            if (kt < 10) {
                int kbase = kt * 32 + quad * 8;
                h8 af;
                if (kt < 9) {
                    f4 u0 = *(const f4*)(embrow + kbase);
                    f4 u1 = *(const f4*)(embrow + kbase + 4);
#pragma unroll
                    for (int e = 0; e < 4; e++) { af[e] = (_Float16)u0[e]; af[4+e] = (_Float16)u1[e]; }
                } else {
#pragma unroll
                    for (int e = 0; e < 8; e++) { int kk = kbase + e; af[e] = (_Float16)((kk < 300) ? embrow[kk] : 0.f); }
                }
                int kb = (kt * 4 + quad) * 32;
                a.h0 = MFMA(af, *(const h8*)&whi[(kb + fm) * 8],      a.h0, 0,0,0);
                a.l0 = MFMA(af, *(const h8*)&wlo[(kb + fm) * 8],      a.l0, 0,0,0);
                a.h1 = MFMA(af, *(const h8*)&whi[(kb + 16 + fm) * 8], a.h1, 0,0,0);
                a.l1 = MFMA(af, *(const h8*)&wlo[(kb + 16 + fm) * 8], a.l1, 0,0,0);
            }
        }
        return a;
    };

    // two-pass plain-store reduction into csm[2] (no atomics — R20 proven)
    auto reduce_store = [&](const f4& aH0, const f4& aL0, const f4& aH1, const f4& aL1){
        if (g4 < 2) {
#pragma unroll
            for (int r = 0; r < 4; r++) {
                csm[g4][(mt * 16 + quad * 4 + r) * 33 + fm]      = aH0[r] + aL0[r] * LOSC;
                csm[g4][(mt * 16 + quad * 4 + r) * 33 + 16 + fm] = aH1[r] + aL1[r] * LOSC;
            }
        }
        __syncthreads();
        if (g4 >= 2) {
#pragma unroll
            for (int r = 0; r < 4; r++) {
                csm[g4 - 2][(mt * 16 + quad * 4 + r) * 33 + fm]      += aH0[r] + aL0[r] * LOSC;
                csm[g4 - 2][(mt * 16 + quad * 4 + r) * 33 + 16 + fm] += aH1[r] + aL1[r] * LOSC;
            }
        }
        __syncthreads();
    };

    X4 accx;
    barrier_arrive(flags, tid, bid, 1);
    if (lyr == 0) accx = xgemm(0);
    barrier_wait(flags, tid, 1);

    // --- acquire per-XCD rank (tickets are all-zero now; add is globally ordered after) ---
    if (tid == 0) {
        int r = __hip_atomic_fetch_add(aux + xcd, 1, __ATOMIC_RELAXED, __HIP_MEMORY_SCOPE_AGENT);
        srank = r & 31;
    }
    __syncthreads();
    const int rank = srank;

    for (int p = 0; p <= Tt; ++p) {
        const int par = p & 1, wpar = 1 - par;

        // ---- R21 import: XCD's 32 blocks cooperatively copy the current-parity
        //      h0+h1 planes (2 x 128 KB) into XCD-private staging. rank slice =
        //      2048 u16 per plane; 256 threads x 16B per plane. ----
        {
            const int pb = par * HPAR;
            if (tid < 512) {
                int plane = tid >> 8;            // 0: h0, 1: h1
                int t = tid & 255;
                int off = rank * 2048 + t * 8;
                h8 v = ldH(rsrc, (plane ? H1OFF : H0OFF) + pb + off);
                *(h8*)(ws + stb + plane * HPAR + off) = v;
            }
            __builtin_amdgcn_s_waitcnt(0);
            __syncthreads();
            if (tid == 0)
                __hip_atomic_store(xf + rank, p + 2, __ATOMIC_RELAXED, __HIP_MEMORY_SCOPE_AGENT);
            if (tid < 32)
                while (__hip_atomic_load(xf + tid, __ATOMIC_RELAXED, __HIP_MEMORY_SCOPE_AGENT) < p + 2)
                    __builtin_amdgcn_s_sleep(1);
            __syncthreads();
        }

        if (lyr == 1) {
            if (p >= 1) {   // ---- layer 1 for t=p-1 : g1 = [h0(p-1) | h1(p-2)] @ W1 ----
                f4 aH0 = (f4){0,0,0,0}, aL0 = aH0, aH1 = aH0, aL1 = aH0;
                // k-quarters: g4 0,1 -> h0 half (kt 0..15); g4 2,3 -> h1 half (kt 16..31)
                const int hpo = stb + (g4 >= 2 ? HPAR : 0) + arow * 8;
                const int ktbase = g4 * 8;                   // global kt base
                const int ltbase = (g4 & 1) * 8;             // local kt within the h half
                h8 af[8];
#pragma unroll
                for (int ktl = 0; ktl < 8; ktl++)
                    af[ktl] = ldG(rsrc, hpo + ((ltbase + ktl) * 4 + quad) * 1024);
#pragma unroll
                for (int ktl = 0; ktl < 8; ktl++) {
                    int kb = ((ktbase + ktl) * 4 + quad) * 32;
                    aH0 = MFMA(af[ktl], *(const h8*)&whi[(kb + fm) * 8],      aH0, 0,0,0);
                    aL0 = MFMA(af[ktl], *(const h8*)&wlo[(kb + fm) * 8],      aL0, 0,0,0);
                    aH1 = MFMA(af[ktl], *(const h8*)&whi[(kb + 16 + fm) * 8], aH1, 0,0,0);
                    aL1 = MFMA(af[ktl], *(const h8*)&wlo[(kb + 16 + fm) * 8], aL1, 0,0,0);
                }
                reduce_store(aH0, aL0, aH1, aL1);
                if (tid < 512) {   // gates: col n = gate*8 + hc; sum the 2 planes + reg bias
                    float gi = csm[0][actm * 33 + acthc]      + csm[1][actm * 33 + acthc]      + bi;
                    float gj = csm[0][actm * 33 + 8 + acthc]  + csm[1][actm * 33 + 8 + acthc]  + bj;
                    float gf = csm[0][actm * 33 + 16 + acthc] + csm[1][actm * 33 + 16 + acthc] + bf;
                    float go = csm[0][actm * 33 + 24 + acthc] + csm[1][actm * 33 + 24 + acthc] + bo;
                    cs = cs * sigm(gf + 1.f) + sigm(gi) * tanhf(gj);
                    float hv = tanhf(cs) * sigm(go);
                    u16 hb = h_bits(hv);
                    unsigned int pa = (unsigned int)hb | (((unsigned int)(u16)__shfl_xor((int)hb, 1, 64)) << 16);
                    if (!(acthc & 1)) {
                        u16* base = ws + H1OFF + wpar * HPAR + cg * 1024 + actrow * 8;
                        __hip_atomic_store((unsigned int*)(base + acthc), pa, __ATOMIC_RELAXED, __HIP_MEMORY_SCOPE_AGENT);
                    }
                }
            }
        } else {
            if (p < Tt) {   // ---- layer 0 h-part for t=p (x-part already in accx) ----
                f4 aH0 = accx.h0, aL0 = accx.l0, aH1 = accx.h1, aL1 = accx.l1;
                const int h0o = stb + arow * 8;
                h8 af[4];
#pragma unroll
                for (int ktl = 0; ktl < 4; ktl++) {
                    int kt = 10 + g4 * 4 + ktl;       // kt 10..25 in quarters
                    af[ktl] = ldG(rsrc, h0o + ((kt - 10) * 4 + quad) * 1024);
                }
#pragma unroll
                for (int ktl = 0; ktl < 4; ktl++) {
                    int kt = 10 + g4 * 4 + ktl;
                    int kb = (kt * 4 + quad) * 32;
                    aH0 = MFMA(af[ktl], *(const h8*)&whi[(kb + fm) * 8],      aH0, 0,0,0);
                    aL0 = MFMA(af[ktl], *(const h8*)&wlo[(kb + fm) * 8],      aL0, 0,0,0);
                    aH1 = MFMA(af[ktl], *(const h8*)&whi[(kb + 16 + fm) * 8], aH1, 0,0,0);
                    aL1 = MFMA(af[ktl], *(const h8*)&wlo[(kb + 16 + fm) * 8], aL1, 0,0,0);
                }
                reduce_store(aH0, aL0, aH1, aL1);
                if (tid < 512) {
                    float gi = csm[0][actm * 33 + acthc]      + csm[1][actm * 33 + acthc]      + bi;
                    float gj = csm[0][actm * 33 + 8 + acthc]  + csm[1][actm * 33 + 8 + acthc]  + bj;
                    float gf = csm[0][actm * 33 + 16 + acthc] + csm[1][actm * 33 + 16 + acthc] + bf;
                    float go = csm[0][actm * 33 + 24 + acthc] + csm[1][actm * 33 + 24 + acthc] + bo;
                    cs = cs * sigm(gf + 1.f) + sigm(gi) * tanhf(gj);
                    float hv = tanhf(cs) * sigm(go);
                    u16 hb = h_bits(hv);
                    unsigned int pa = (unsigned int)hb | (((unsigned int)(u16)__shfl_xor((int)hb, 1, 64)) << 16);
                    if (!(acthc & 1)) {
                        u16* base = ws + H0OFF + wpar * HPAR + cg * 1024 + actrow * 8;
                        __hip_atomic_store((unsigned int*)(base + acthc), pa, __ATOMIC_RELAXED, __HIP_MEMORY_SCOPE_AGENT);
                    }
                }
            }
        }

        barrier_arrive(flags, tid, bid, p + 2);
        if (lyr == 0 && p + 1 < Tt) accx = xgemm(p + 1);
        barrier_wait(flags, tid, p + 2);
    }

    // ---- final logits: h1(T-1) lives in parity 1 (frag-major addressing, unchanged) ----
    if (bid == 0 && tid < 256) {
        int b = tid >> 1, jj = tid & 1;
        float sum = bd[jj];
        const u16* hh = ws + H1OFF + 1 * HPAR;
        for (int g = 0; g < 64; g++) {
#pragma unroll
            for (int j4 = 0; j4 < 8; j4 += 4) {
                ull u = __hip_atomic_load((const ull*)(hh + (g * 128 + b) * 8 + j4),
                                          __ATOMIC_RELAXED, __HIP_MEMORY_SCOPE_AGENT);
#pragma unroll
                for (int e = 0; e < 4; e++)
                    sum += bits_f((u16)(u >> (16 * e))) * Wd[(g * 8 + j4 + e) * 2 + jj];
            }
        }
        out[b * 2 + jj] = sum;
    }
}

extern "C" void kernel_launch(void* const* d_in, const int* in_sizes, int n_in,
                              void* d_out, int out_size, void* d_ws, size_t ws_size,
                              hipStream_t stream) {
    const int*   x   = (const int*)d_in[0];
    const float* emb = (const float*)d_in[1];
    const float* W0  = (const float*)d_in[2];
    const float* b0  = (const float*)d_in[3];
    const float* W1  = (const float*)d_in[4];
    const float* b1  = (const float*)d_in[5];
    const float* Wd  = (const float*)d_in[6];
    const float* bd  = (const float*)d_in[7];
    float* out = (float*)d_out;
    u16* ws = (u16*)d_ws;

    void* args[] = { (void*)&x, (void*)&emb, (void*)&W0, (void*)&b0, (void*)&W1,
                     (void*)&b1, (void*)&Wd, (void*)&bd, (void*)&out, (void*)&ws };
    hipLaunchCooperativeKernel((void*)lstm_coop, dim3(256), dim3(1024), args, 0, stream);
}

// Round 16
// 1761.004 us; speedup vs baseline: 1.3166x; 1.3166x over previous
//
#include <hip/hip_runtime.h>

// Problem constants
#define Tt 256

// ws layout in unsigned shorts (fp16 bit patterns / ints for flags):
//  flags : ints [0..256) global arrival flags (4B packed)
//  h replicas: 8 copies x [h0: 2 parity planes | h1: 2 parity planes]
//    copy c base = H0OFF + c*4*HPAR ; h0 plane at +par*HPAR ; h1 at +2*HPAR+par*HPAR
//    (R22: producer-side 8x replication — consumers read copy[xcd])
#define FLAGS_SHORTS 16384
#define H0OFF  16384
#define HPAR   (64*128*8)            // u16 per parity plane = 65536
#define HCOPY  (4*HPAR)              // u16 per replica (h0par0,h0par1,h1par0,h1par1)

typedef _Float16 h8 __attribute__((ext_vector_type(8)));
typedef float    f4 __attribute__((ext_vector_type(4)));
typedef unsigned long long ull;
typedef unsigned short u16;

#define MFMA __builtin_amdgcn_mfma_f32_16x16x32_f16
#define LOSC (1.0f/1024.0f)

__device__ inline u16 h_bits(float f){ union{_Float16 h; u16 s;} u; u.h=(_Float16)f; return u.s; }
__device__ inline float bits_f(u16 s){ union{u16 s2; _Float16 h;} u; u.s2=s; return (float)u.h; }
__device__ inline float sigm(float x){ return 1.f/(1.f+expf(-x)); }

// ---- R14 (proven): single-transaction 16B coherent load (SC0|SC1, MALL-served) ----
__device__ inline __amdgpu_buffer_rsrc_t make_rsrc(const void* base){
    return __builtin_amdgcn_make_buffer_rsrc((void*)base, /*stride*/(short)0,
                                             /*num_records*/0xFFFFFFFFu,
                                             /*flags word3*/0x00020000);
}
__device__ inline h8 ldH(__amdgpu_buffer_rsrc_t rsrc, int u16idx){
    auto d = __builtin_amdgcn_raw_buffer_load_b128(rsrc, u16idx * 2, 0, 17 /*SC0|SC1*/);
    h8 v; __builtin_memcpy(&v, &d, 16);
    return v;
}

// Fence-free global split barrier — proven structure (threads 0..255 poll packed flags).
__device__ inline void barrier_arrive(int* __restrict__ flags, int tid, int bid, int target) {
    __builtin_amdgcn_s_waitcnt(0);
    __syncthreads();
    if (tid == 0)
        __hip_atomic_store(flags + bid, target, __ATOMIC_RELAXED, __HIP_MEMORY_SCOPE_AGENT);
}
__device__ inline void barrier_wait(int* __restrict__ flags, int tid, int target) {
    if (tid < 256)
        while (__hip_atomic_load(flags + tid, __ATOMIC_RELAXED, __HIP_MEMORY_SCOPE_AGENT) < target)
            __builtin_amdgcn_s_sleep(4);
    __syncthreads();
}

struct X4 { f4 h0, l0, h1, l1; };

// ---------------- persistent cooperative LSTM kernel ----------------
// grid 256 x 1024 (1 block/CU, 16 waves): R8-proven geometry, R20-proven wlo-in-LDS
// (= R14 anchor, 1665 us). R15's serial staging reverted (import+intra-barrier cost
// ~2.5 us/phase > the saving; its xcd-detection machinery was proven correct though).
// R22 change (single variable): PRODUCER-SIDE 8x h REPLICATION.
//   Theory: the 24 MB/phase coherent broadcast hammers the SAME 512 KB (~370
//   requests/line/phase) — if the MALL serializes per-line (read-combining/bank),
//   spreading consumers over 8 address-disjoint replicas (one per XCD) relieves it.
//   Producers store each h value to all 8 copies (256 KB -> 2 MB/phase of relaxed
//   fire-and-forget stores, drained by barrier_arrive's waitcnt(0) — no new sync);
//   consumers read copy[xcd] via the identical ldH protocol and indexing.
//   Discriminator: per-line-bound -> phase ~3-4 us; aggregate-rate-bound -> flat.
__global__ __launch_bounds__(1024, 1) void lstm_coop(
    const int* __restrict__ x, const float* __restrict__ emb,
    const float* __restrict__ W0, const float* __restrict__ b0,
    const float* __restrict__ W1, const float* __restrict__ b1,
    const float* __restrict__ Wd, const float* __restrict__ bd,
    float* __restrict__ out, u16* __restrict__ ws) {

    const int tid  = threadIdx.x;
    const int lane = tid & 63;
    const int wave = tid >> 6;        // 0..15
    const int mt   = wave & 3;        // m-tile (16 rows each)
    const int g4   = wave >> 2;       // k-quarter 0..3
    const int quad = lane >> 4;       // 0..3 : k-chunk of 8 in frags
    const int fm   = lane & 15;       // A: m, B: n, C/D: col
    const int bid  = blockIdx.x;
    const int lyr  = bid & 1;
    const int inner= bid >> 1;
    const int bq   = inner >> 6;
    const int cg   = inner & 63;

    __shared__ u16   whi[128 * 32 * 8];   // 65,536 B (lyr0 uses first 104*32*8)
    __shared__ u16   wlo[128 * 32 * 8];   // 65,536 B lo-plane
    __shared__ float csm[2][64 * 33];     // 16,896 B -> 147,968 B total

    int* flags = (int*)ws;
    const __amdgpu_buffer_rsrc_t rsrc = make_rsrc(ws);

    int xcd;
    asm("s_getreg_b32 %0, hwreg(HW_REG_XCC_ID)" : "=s"(xcd));
    xcd &= 7;
    const int rb = H0OFF + xcd * HCOPY;   // this XCD's read replica base (u16 idx)

    // --- fill LDS hi+lo planes of this block's layer & 32 gate columns, layout [kg][n][8] ---
    if (lyr == 0) {
        for (int i = tid; i < 104 * 32 * 8; i += 1024) {
            int kg = i >> 8; int rem = i & 255; int n = rem >> 3; int j = rem & 7;
            int k = kg * 8 + j;
            int col = ((n >> 3) << 9) + (cg << 3) + (n & 7);
            float w = 0.f;
            if (k < 300) w = W0[k * 2048 + col];
            else if (k >= 320) w = W0[(k - 20) * 2048 + col];
            _Float16 wh = (_Float16)w;
            union{_Float16 h; u16 s;} uh; uh.h = wh;
            whi[i] = uh.s;
            wlo[i] = h_bits((w - (float)wh) * 1024.0f);
        }
    } else {
        for (int i = tid; i < 128 * 32 * 8; i += 1024) {
            int kg = i >> 8; int rem = i & 255; int n = rem >> 3; int j = rem & 7;
            int k = kg * 8 + j;
            int col = ((n >> 3) << 9) + (cg << 3) + (n & 7);
            float w = W1[k * 2048 + col];
            _Float16 wh = (_Float16)w;
            union{_Float16 h; u16 s;} uh; uh.h = wh;
            whi[i] = uh.s;
            wlo[i] = h_bits((w - (float)wh) * 1024.0f);
        }
    }

    // h addressing within a replica (frag-major, unchanged): u16 idx = cg*1024 + row*8 + c
    // --- zero-init own slice in ALL 8 replicas: lyr0 -> h0 par0 ; lyr1 -> h1 par1 ---
    if (tid < 256) {
        int row = bq * 64 + (tid >> 2);
        int c = (tid & 3) << 1;
        int off = (lyr ? 2 * HPAR + 1 * HPAR : 0) + cg * 1024 + row * 8 + c;
#pragma unroll
        for (int cpy = 0; cpy < 8; cpy++) {
            unsigned int* pz = (unsigned int*)(ws + H0OFF + cpy * HCOPY + off);
            __hip_atomic_store(pz, 0u, __ATOMIC_RELAXED, __HIP_MEMORY_SCOPE_AGENT);
        }
    }

    const int arow = bq * 64 + mt * 16 + fm;   // A-frag row (batch index)
    // act cell: ONE cell per thread for tid<512: (row actm 0..63, h-col acthc 0..7)
    const int actm   = tid >> 3;
    const int acthc  = tid & 7;
    const int actrow = bq * 64 + actm;
    const int ca = (cg << 3) + acthc;          // global h-col of the cell

    const float bi = lyr ? b1[ca]        : b0[ca];
    const float bj = lyr ? b1[512 + ca]  : b0[512 + ca];
    const float bf = lyr ? b1[1024 + ca] : b0[1024 + ca];
    const float bo = lyr ? b1[1536 + ca] : b0[1536 + ca];

    float cs = 0.f;

    // x-part GEMM of layer 0 for timestep pp; this wave's k-quarter: kt = ktl*4 + g4 (kt<10).
    auto xgemm = [&](int pp) -> X4 {
        X4 a; a.h0 = (f4){0,0,0,0}; a.l0 = a.h0; a.h1 = a.h0; a.l1 = a.h0;
        int xi = x[arow * Tt + pp];
        xi = (xi < 0) ? 0 : ((xi >= 50000) ? 49999 : xi);
        const float* embrow = emb + (size_t)xi * 300;
#pragma unroll
        for (int ktl = 0; ktl < 3; ktl++) {
            int kt = ktl * 4 + g4;
            if (kt < 10) {
                int kbase = kt * 32 + quad * 8;
                h8 af;
                if (kt < 9) {
                    f4 u0 = *(const f4*)(embrow + kbase);
                    f4 u1 = *(const f4*)(embrow + kbase + 4);
#pragma unroll
                    for (int e = 0; e < 4; e++) { af[e] = (_Float16)u0[e]; af[4+e] = (_Float16)u1[e]; }
                } else {
#pragma unroll
                    for (int e = 0; e < 8; e++) { int kk = kbase + e; af[e] = (_Float16)((kk < 300) ? embrow[kk] : 0.f); }
                }
                int kb = (kt * 4 + quad) * 32;
                a.h0 = MFMA(af, *(const h8*)&whi[(kb + fm) * 8],      a.h0, 0,0,0);
                a.l0 = MFMA(af, *(const h8*)&wlo[(kb + fm) * 8],      a.l0, 0,0,0);
                a.h1 = MFMA(af, *(const h8*)&whi[(kb + 16 + fm) * 8], a.h1, 0,0,0);
                a.l1 = MFMA(af, *(const h8*)&wlo[(kb + 16 + fm) * 8], a.l1, 0,0,0);
            }
        }
        return a;
    };

    // two-pass plain-store reduction into csm[2] (no atomics — R20 proven)
    auto reduce_store = [&](const f4& aH0, const f4& aL0, const f4& aH1, const f4& aL1){
        if (g4 < 2) {
#pragma unroll
            for (int r = 0; r < 4; r++) {
                csm[g4][(mt * 16 + quad * 4 + r) * 33 + fm]      = aH0[r] + aL0[r] * LOSC;
                csm[g4][(mt * 16 + quad * 4 + r) * 33 + 16 + fm] = aH1[r] + aL1[r] * LOSC;
            }
        }
        __syncthreads();
        if (g4 >= 2) {
#pragma unroll
            for (int r = 0; r < 4; r++) {
                csm[g4 - 2][(mt * 16 + quad * 4 + r) * 33 + fm]      += aH0[r] + aL0[r] * LOSC;
                csm[g4 - 2][(mt * 16 + quad * 4 + r) * 33 + 16 + fm] += aH1[r] + aL1[r] * LOSC;
            }
        }
        __syncthreads();
    };

    // store h value to all 8 replicas (relaxed agent stores, drained at barrier_arrive)
    auto store_h = [&](int lyroff, int wpar, unsigned int pa, int acthc_) {
        int off = lyroff + wpar * HPAR + cg * 1024 + actrow * 8 + acthc_;
#pragma unroll
        for (int cpy = 0; cpy < 8; cpy++)
            __hip_atomic_store((unsigned int*)(ws + H0OFF + cpy * HCOPY + off), pa,
                               __ATOMIC_RELAXED, __HIP_MEMORY_SCOPE_AGENT);
    };

    X4 accx;
    barrier_arrive(flags, tid, bid, 1);
    if (lyr == 0) accx = xgemm(0);
    barrier_wait(flags, tid, 1);

    for (int p = 0; p <= Tt; ++p) {
        const int par = p & 1, wpar = 1 - par;

        if (lyr == 1) {
            if (p >= 1) {   // ---- layer 1 for t=p-1 : g1 = [h0(p-1) | h1(p-2)] @ W1 ----
                f4 aH0 = (f4){0,0,0,0}, aL0 = aH0, aH1 = aH0, aL1 = aH0;
                // k-quarters: g4 0,1 -> h0 half (kt 0..15); g4 2,3 -> h1 half (kt 16..31)
                const int hpo = rb + (g4 >= 2 ? 2 * HPAR : 0) + par * HPAR + arow * 8;
                const int ktbase = g4 * 8;                   // global kt base
                const int ltbase = (g4 & 1) * 8;             // local kt within the h half
                h8 af[8];
#pragma unroll
                for (int ktl = 0; ktl < 8; ktl++)
                    af[ktl] = ldH(rsrc, hpo + ((ltbase + ktl) * 4 + quad) * 1024);
#pragma unroll
                for (int ktl = 0; ktl < 8; ktl++) {
                    int kb = ((ktbase + ktl) * 4 + quad) * 32;
                    aH0 = MFMA(af[ktl], *(const h8*)&whi[(kb + fm) * 8],      aH0, 0,0,0);
                    aL0 = MFMA(af[ktl], *(const h8*)&wlo[(kb + fm) * 8],      aL0, 0,0,0);
                    aH1 = MFMA(af[ktl], *(const h8*)&whi[(kb + 16 + fm) * 8], aH1, 0,0,0);
                    aL1 = MFMA(af[ktl], *(const h8*)&wlo[(kb + 16 + fm) * 8], aL1, 0,0,0);
                }
                reduce_store(aH0, aL0, aH1, aL1);
                if (tid < 512) {   // gates: col n = gate*8 + hc; sum the 2 planes + reg bias
                    float gi = csm[0][actm * 33 + acthc]      + csm[1][actm * 33 + acthc]      + bi;
                    float gj = csm[0][actm * 33 + 8 + acthc]  + csm[1][actm * 33 + 8 + acthc]  + bj;
                    float gf = csm[0][actm * 33 + 16 + acthc] + csm[1][actm * 33 + 16 + acthc] + bf;
                    float go = csm[0][actm * 33 + 24 + acthc] + csm[1][actm * 33 + 24 + acthc] + bo;
                    cs = cs * sigm(gf + 1.f) + sigm(gi) * tanhf(gj);
                    float hv = tanhf(cs) * sigm(go);
                    u16 hb = h_bits(hv);
                    unsigned int pa = (unsigned int)hb | (((unsigned int)(u16)__shfl_xor((int)hb, 1, 64)) << 16);
                    if (!(acthc & 1)) store_h(2 * HPAR, wpar, pa, acthc);
                }
            }
        } else {
            if (p < Tt) {   // ---- layer 0 h-part for t=p (x-part already in accx) ----
                f4 aH0 = accx.h0, aL0 = accx.l0, aH1 = accx.h1, aL1 = accx.l1;
                const int h0o = rb + par * HPAR + arow * 8;
                h8 af[4];
#pragma unroll
                for (int ktl = 0; ktl < 4; ktl++) {
                    int kt = 10 + g4 * 4 + ktl;       // kt 10..25 in quarters
                    af[ktl] = ldH(rsrc, h0o + ((kt - 10) * 4 + quad) * 1024);
                }
#pragma unroll
                for (int ktl = 0; ktl < 4; ktl++) {
                    int kt = 10 + g4 * 4 + ktl;
                    int kb = (kt * 4 + quad) * 32;
                    aH0 = MFMA(af[ktl], *(const h8*)&whi[(kb + fm) * 8],      aH0, 0,0,0);
                    aL0 = MFMA(af[ktl], *(const h8*)&wlo[(kb + fm) * 8],      aL0, 0,0,0);
                    aH1 = MFMA(af[ktl], *(const h8*)&whi[(kb + 16 + fm) * 8], aH1, 0,0,0);
                    aL1 = MFMA(af[ktl], *(const h8*)&wlo[(kb + 16 + fm) * 8], aL1, 0,0,0);
                }
                reduce_store(aH0, aL0, aH1, aL1);
                if (tid < 512) {
                    float gi = csm[0][actm * 33 + acthc]      + csm[1][actm * 33 + acthc]      + bi;
                    float gj = csm[0][actm * 33 + 8 + acthc]  + csm[1][actm * 33 + 8 + acthc]  + bj;
                    float gf = csm[0][actm * 33 + 16 + acthc] + csm[1][actm * 33 + 16 + acthc] + bf;
                    float go = csm[0][actm * 33 + 24 + acthc] + csm[1][actm * 33 + 24 + acthc] + bo;
                    cs = cs * sigm(gf + 1.f) + sigm(gi) * tanhf(gj);
                    float hv = tanhf(cs) * sigm(go);
                    u16 hb = h_bits(hv);
                    unsigned int pa = (unsigned int)hb | (((unsigned int)(u16)__shfl_xor((int)hb, 1, 64)) << 16);
                    if (!(acthc & 1)) store_h(0, wpar, pa, acthc);
                }
            }
        }

        barrier_arrive(flags, tid, bid, p + 2);
        if (lyr == 0 && p + 1 < Tt) accx = xgemm(p + 1);
        barrier_wait(flags, tid, p + 2);
    }

    // ---- final logits: h1(T-1) lives in copy 0, h1 section, parity 1 ----
    if (bid == 0 && tid < 256) {
        int b = tid >> 1, jj = tid & 1;
        float sum = bd[jj];
        const u16* hh = ws + H0OFF + 2 * HPAR + 1 * HPAR;
        for (int g = 0; g < 64; g++) {
#pragma unroll
            for (int j4 = 0; j4 < 8; j4 += 4) {
                ull u = __hip_atomic_load((const ull*)(hh + (g * 128 + b) * 8 + j4),
                                          __ATOMIC_RELAXED, __HIP_MEMORY_SCOPE_AGENT);
#pragma unroll
                for (int e = 0; e < 4; e++)
                    sum += bits_f((u16)(u >> (16 * e))) * Wd[(g * 8 + j4 + e) * 2 + jj];
            }
        }
        out[b * 2 + jj] = sum;
    }
}

extern "C" void kernel_launch(void* const* d_in, const int* in_sizes, int n_in,
                              void* d_out, int out_size, void* d_ws, size_t ws_size,
                              hipStream_t stream) {
    const int*   x   = (const int*)d_in[0];
    const float* emb = (const float*)d_in[1];
    const float* W0  = (const float*)d_in[2];
    const float* b0  = (const float*)d_in[3];
    const float* W1  = (const float*)d_in[4];
    const float* b1  = (const float*)d_in[5];
    const float* Wd  = (const float*)d_in[6];
    const float* bd  = (const float*)d_in[7];
    float* out = (float*)d_out;
    u16* ws = (u16*)d_ws;

    void* args[] = { (void*)&x, (void*)&emb, (void*)&W0, (void*)&b0, (void*)&W1,
                     (void*)&b1, (void*)&Wd, (void*)&bd, (void*)&out, (void*)&ws };
    hipLaunchCooperativeKernel((void*)lstm_coop, dim3(256), dim3(1024), args, 0, stream);
}

// Round 17
// 1745.422 us; speedup vs baseline: 1.3284x; 1.0089x over previous
//
#include <hip/hip_runtime.h>

// Problem constants
#define Tt 256

// ws layout in unsigned shorts (fp16 bit patterns / ints for flags):
//  flags : ints [0..256) arrival flags (4B packed)
//  h0 [2 parity][64 g][128 row][8]  fp16 frag-major     (g = col>>3)
//  h1 same
// R20/R14-anchor: wlo lives in LDS (computed in fill loop); prepack deleted.
#define FLAGS_SHORTS 16384
#define H0OFF  16384
#define H1OFF  (H0OFF + 2*64*128*8)
#define HPAR   (64*128*8)            // u16 per parity plane = 65536

typedef _Float16 h8 __attribute__((ext_vector_type(8)));
typedef float    f4 __attribute__((ext_vector_type(4)));
typedef unsigned long long ull;
typedef unsigned short u16;

#define MFMA __builtin_amdgcn_mfma_f32_16x16x32_f16
#define LOSC (1.0f/1024.0f)

__device__ inline u16 h_bits(float f){ union{_Float16 h; u16 s;} u; u.h=(_Float16)f; return u.s; }
__device__ inline float bits_f(u16 s){ union{u16 s2; _Float16 h;} u; u.s2=s; return (float)u.h; }
__device__ inline float sigm(float x){ return 1.f/(1.f+expf(-x)); }

// ---- R14 (proven): single-transaction 16B coherent load (SC0|SC1, MALL-served) ----
// Ordinary buffer load: vmcnt-tracked, ordered against the phase barrier by
// __syncthreads — NOT subject to the R8/R9 relaxed-atomic migration hazard.
__device__ inline __amdgpu_buffer_rsrc_t make_rsrc(const void* base){
    return __builtin_amdgcn_make_buffer_rsrc((void*)base, /*stride*/(short)0,
                                             /*num_records*/0xFFFFFFFFu,
                                             /*flags word3*/0x00020000);
}
__device__ inline h8 ldH(__amdgpu_buffer_rsrc_t rsrc, int u16idx){
    auto d = __builtin_amdgcn_raw_buffer_load_b128(rsrc, u16idx * 2, 0, 17 /*SC0|SC1*/);
    h8 v; __builtin_memcpy(&v, &d, 16);
    return v;
}

// Fence-free global split barrier — proven structure (threads 0..255 poll packed flags).
// 256 blocks: thread tid polls flags[tid]. Initial poison (0xAAAAAAAA<0) needs no init.
// s_sleep(4) retained from R3 (proven passing).
__device__ inline void barrier_arrive(int* __restrict__ flags, int tid, int bid, int target) {
    __builtin_amdgcn_s_waitcnt(0);
    __syncthreads();
    if (tid == 0)
        __hip_atomic_store(flags + bid, target, __ATOMIC_RELAXED, __HIP_MEMORY_SCOPE_AGENT);
}
__device__ inline void barrier_wait(int* __restrict__ flags, int tid, int target) {
    if (tid < 256)
        while (__hip_atomic_load(flags + tid, __ATOMIC_RELAXED, __HIP_MEMORY_SCOPE_AGENT) < target)
            __builtin_amdgcn_s_sleep(4);
    __syncthreads();
}

struct X4 { f4 h0, l0, h1, l1; };

// ---------------- persistent cooperative LSTM kernel ----------------
// grid 256 x 1024 (1 block/CU, 16 waves = 4/SIMD): bid = inner*2 + lyr.
//   lyr = bid&1 : 0 -> layer-0 duties, 1 -> layer-1 duties (proven split)
//   inner = bid>>1 in [0,128): bq = inner>>6 (64-row batch half), cg = inner&63
//   (8 h-cols -> 32 gate-cols). R8-proven geometry + R20-proven wlo-in-LDS.
// R23 = REVERT TO R14 (best: 1665 us). R15 (per-XCD staging: serial import+barrier
// cost > save) and R16 (8x replication: read time flat, store cost added) both
// falsified their theories; the coherent path is AGGREGATE-REQUEST-RATE bound
// (~4.4 TB/s effective), and the 24 MB/phase volume is pinned by LDS-limited
// output tiling. This resubmit restores the proven optimum.
__global__ __launch_bounds__(1024, 1) void lstm_coop(
    const int* __restrict__ x, const float* __restrict__ emb,
    const float* __restrict__ W0, const float* __restrict__ b0,
    const float* __restrict__ W1, const float* __restrict__ b1,
    const float* __restrict__ Wd, const float* __restrict__ bd,
    float* __restrict__ out, u16* __restrict__ ws) {

    const int tid  = threadIdx.x;
    const int lane = tid & 63;
    const int wave = tid >> 6;        // 0..15
    const int mt   = wave & 3;        // m-tile (16 rows each)
    const int g4   = wave >> 2;       // k-quarter 0..3
    const int quad = lane >> 4;       // 0..3 : k-chunk of 8 in frags
    const int fm   = lane & 15;       // A: m, B: n, C/D: col
    const int bid  = blockIdx.x;
    const int lyr  = bid & 1;
    const int inner= bid >> 1;
    const int bq   = inner >> 6;
    const int cg   = inner & 63;

    __shared__ u16   whi[128 * 32 * 8];   // 65,536 B (lyr0 uses first 104*32*8)
    __shared__ u16   wlo[128 * 32 * 8];   // 65,536 B lo-plane
    __shared__ float csm[2][64 * 33];     // 16,896 B -> 147,968 B total

    int* flags = (int*)ws;
    const __amdgpu_buffer_rsrc_t rsrc = make_rsrc(ws);

    // --- fill LDS hi+lo planes of this block's layer & 32 gate columns, layout [kg][n][8] ---
    if (lyr == 0) {
        for (int i = tid; i < 104 * 32 * 8; i += 1024) {
            int kg = i >> 8; int rem = i & 255; int n = rem >> 3; int j = rem & 7;
            int k = kg * 8 + j;
            int col = ((n >> 3) << 9) + (cg << 3) + (n & 7);
            float w = 0.f;
            if (k < 300) w = W0[k * 2048 + col];
            else if (k >= 320) w = W0[(k - 20) * 2048 + col];
            _Float16 wh = (_Float16)w;
            union{_Float16 h; u16 s;} uh; uh.h = wh;
            whi[i] = uh.s;
            wlo[i] = h_bits((w - (float)wh) * 1024.0f);
        }
    } else {
        for (int i = tid; i < 128 * 32 * 8; i += 1024) {
            int kg = i >> 8; int rem = i & 255; int n = rem >> 3; int j = rem & 7;
            int k = kg * 8 + j;
            int col = ((n >> 3) << 9) + (cg << 3) + (n & 7);
            float w = W1[k * 2048 + col];
            _Float16 wh = (_Float16)w;
            union{_Float16 h; u16 s;} uh; uh.h = wh;
            whi[i] = uh.s;
            wlo[i] = h_bits((w - (float)wh) * 1024.0f);
        }
    }

    // h addressing (frag-major, unchanged): plane u16 index = cg*1024 + row*8 + c, c in [0,8)
    // --- zero-init own slice: lyr0 -> h0 parity 0 ; lyr1 -> h1 parity 1 (64 rows x 8 cols) ---
    if (tid < 256) {
        int row = bq * 64 + (tid >> 2);
        int c = (tid & 3) << 1;
        unsigned int* pz = (unsigned int*)(ws + (lyr ? H1OFF + 1 * HPAR : H0OFF + 0 * HPAR)
                                           + cg * 1024 + row * 8 + c);
        __hip_atomic_store(pz, 0u, __ATOMIC_RELAXED, __HIP_MEMORY_SCOPE_AGENT);
    }

    const int arow = bq * 64 + mt * 16 + fm;   // A-frag row (batch index)
    // act cell: ONE cell per thread for tid<512: (row actm 0..63, h-col acthc 0..7)
    const int actm   = tid >> 3;
    const int acthc  = tid & 7;
    const int actrow = bq * 64 + actm;
    const int ca = (cg << 3) + acthc;          // global h-col of the cell

    const float bi = lyr ? b1[ca]        : b0[ca];
    const float bj = lyr ? b1[512 + ca]  : b0[512 + ca];
    const float bf = lyr ? b1[1024 + ca] : b0[1024 + ca];
    const float bo = lyr ? b1[1536 + ca] : b0[1536 + ca];

    float cs = 0.f;

    // x-part GEMM of layer 0 for timestep pp; this wave's k-quarter: kt = ktl*4 + g4 (kt<10).
    auto xgemm = [&](int pp) -> X4 {
        X4 a; a.h0 = (f4){0,0,0,0}; a.l0 = a.h0; a.h1 = a.h0; a.l1 = a.h0;
        int xi = x[arow * Tt + pp];
        xi = (xi < 0) ? 0 : ((xi >= 50000) ? 49999 : xi);
        const float* embrow = emb + (size_t)xi * 300;
#pragma unroll
        for (int ktl = 0; ktl < 3; ktl++) {
            int kt = ktl * 4 + g4;
            if (kt < 10) {
                int kbase = kt * 32 + quad * 8;
                h8 af;
                if (kt < 9) {
                    f4 u0 = *(const f4*)(embrow + kbase);
                    f4 u1 = *(const f4*)(embrow + kbase + 4);
#pragma unroll
                    for (int e = 0; e < 4; e++) { af[e] = (_Float16)u0[e]; af[4+e] = (_Float16)u1[e]; }
                } else {
#pragma unroll
                    for (int e = 0; e < 8; e++) { int kk = kbase + e; af[e] = (_Float16)((kk < 300) ? embrow[kk] : 0.f); }
                }
                int kb = (kt * 4 + quad) * 32;
                a.h0 = MFMA(af, *(const h8*)&whi[(kb + fm) * 8],      a.h0, 0,0,0);
                a.l0 = MFMA(af, *(const h8*)&wlo[(kb + fm) * 8],      a.l0, 0,0,0);
                a.h1 = MFMA(af, *(const h8*)&whi[(kb + 16 + fm) * 8], a.h1, 0,0,0);
                a.l1 = MFMA(af, *(const h8*)&wlo[(kb + 16 + fm) * 8], a.l1, 0,0,0);
            }
        }
        return a;
    };

    // two-pass plain-store reduction into csm[2] (no atomics — R20 proven)
    auto reduce_store = [&](const f4& aH0, const f4& aL0, const f4& aH1, const f4& aL1){
        if (g4 < 2) {
#pragma unroll
            for (int r = 0; r < 4; r++) {
                csm[g4][(mt * 16 + quad * 4 + r) * 33 + fm]      = aH0[r] + aL0[r] * LOSC;
                csm[g4][(mt * 16 + quad * 4 + r) * 33 + 16 + fm] = aH1[r] + aL1[r] * LOSC;
            }
        }
        __syncthreads();
        if (g4 >= 2) {
#pragma unroll
            for (int r = 0; r < 4; r++) {
                csm[g4 - 2][(mt * 16 + quad * 4 + r) * 33 + fm]      += aH0[r] + aL0[r] * LOSC;
                csm[g4 - 2][(mt * 16 + quad * 4 + r) * 33 + 16 + fm] += aH1[r] + aL1[r] * LOSC;
            }
        }
        __syncthreads();
    };

    X4 accx;
    barrier_arrive(flags, tid, bid, 1);
    if (lyr == 0) accx = xgemm(0);
    barrier_wait(flags, tid, 1);

    for (int p = 0; p <= Tt; ++p) {
        const int par = p & 1, wpar = 1 - par;

        if (lyr == 1) {
            if (p >= 1) {   // ---- layer 1 for t=p-1 : g1 = [h0(p-1) | h1(p-2)] @ W1 ----
                f4 aH0 = (f4){0,0,0,0}, aL0 = aH0, aH1 = aH0, aL1 = aH0;
                // k-quarters: g4 0,1 -> h0 half (kt 0..15); g4 2,3 -> h1 half (kt 16..31)
                const int hpo = (g4 >= 2 ? H1OFF : H0OFF) + par * HPAR + arow * 8;
                const int ktbase = g4 * 8;                   // global kt base
                const int ltbase = (g4 & 1) * 8;             // local kt within the h half
                h8 af[8];
#pragma unroll
                for (int ktl = 0; ktl < 8; ktl++)
                    af[ktl] = ldH(rsrc, hpo + ((ltbase + ktl) * 4 + quad) * 1024);
#pragma unroll
                for (int ktl = 0; ktl < 8; ktl++) {
                    int kb = ((ktbase + ktl) * 4 + quad) * 32;
                    aH0 = MFMA(af[ktl], *(const h8*)&whi[(kb + fm) * 8],      aH0, 0,0,0);
                    aL0 = MFMA(af[ktl], *(const h8*)&wlo[(kb + fm) * 8],      aL0, 0,0,0);
                    aH1 = MFMA(af[ktl], *(const h8*)&whi[(kb + 16 + fm) * 8], aH1, 0,0,0);
                    aL1 = MFMA(af[ktl], *(const h8*)&wlo[(kb + 16 + fm) * 8], aL1, 0,0,0);
                }
                reduce_store(aH0, aL0, aH1, aL1);
                if (tid < 512) {   // gates: col n = gate*8 + hc; sum the 2 planes + reg bias
                    float gi = csm[0][actm * 33 + acthc]      + csm[1][actm * 33 + acthc]      + bi;
                    float gj = csm[0][actm * 33 + 8 + acthc]  + csm[1][actm * 33 + 8 + acthc]  + bj;
                    float gf = csm[0][actm * 33 + 16 + acthc] + csm[1][actm * 33 + 16 + acthc] + bf;
                    float go = csm[0][actm * 33 + 24 + acthc] + csm[1][actm * 33 + 24 + acthc] + bo;
                    cs = cs * sigm(gf + 1.f) + sigm(gi) * tanhf(gj);
                    float hv = tanhf(cs) * sigm(go);
                    u16 hb = h_bits(hv);
                    unsigned int pa = (unsigned int)hb | (((unsigned int)(u16)__shfl_xor((int)hb, 1, 64)) << 16);
                    if (!(acthc & 1)) {
                        u16* base = ws + H1OFF + wpar * HPAR + cg * 1024 + actrow * 8;
                        __hip_atomic_store((unsigned int*)(base + acthc), pa, __ATOMIC_RELAXED, __HIP_MEMORY_SCOPE_AGENT);
                    }
                }
            }
        } else {
            if (p < Tt) {   // ---- layer 0 h-part for t=p (x-part already in accx) ----
                f4 aH0 = accx.h0, aL0 = accx.l0, aH1 = accx.h1, aL1 = accx.l1;
                const int h0o = H0OFF + par * HPAR + arow * 8;
                h8 af[4];
#pragma unroll
                for (int ktl = 0; ktl < 4; ktl++) {
                    int kt = 10 + g4 * 4 + ktl;       // kt 10..25 in quarters
                    af[ktl] = ldH(rsrc, h0o + ((kt - 10) * 4 + quad) * 1024);
                }
#pragma unroll
                for (int ktl = 0; ktl < 4; ktl++) {
                    int kt = 10 + g4 * 4 + ktl;
                    int kb = (kt * 4 + quad) * 32;
                    aH0 = MFMA(af[ktl], *(const h8*)&whi[(kb + fm) * 8],      aH0, 0,0,0);
                    aL0 = MFMA(af[ktl], *(const h8*)&wlo[(kb + fm) * 8],      aL0, 0,0,0);
                    aH1 = MFMA(af[ktl], *(const h8*)&whi[(kb + 16 + fm) * 8], aH1, 0,0,0);
                    aL1 = MFMA(af[ktl], *(const h8*)&wlo[(kb + 16 + fm) * 8], aL1, 0,0,0);
                }
                reduce_store(aH0, aL0, aH1, aL1);
                if (tid < 512) {
                    float gi = csm[0][actm * 33 + acthc]      + csm[1][actm * 33 + acthc]      + bi;
                    float gj = csm[0][actm * 33 + 8 + acthc]  + csm[1][actm * 33 + 8 + acthc]  + bj;
                    float gf = csm[0][actm * 33 + 16 + acthc] + csm[1][actm * 33 + 16 + acthc] + bf;
                    float go = csm[0][actm * 33 + 24 + acthc] + csm[1][actm * 33 + 24 + acthc] + bo;
                    cs = cs * sigm(gf + 1.f) + sigm(gi) * tanhf(gj);
                    float hv = tanhf(cs) * sigm(go);
                    u16 hb = h_bits(hv);
                    unsigned int pa = (unsigned int)hb | (((unsigned int)(u16)__shfl_xor((int)hb, 1, 64)) << 16);
                    if (!(acthc & 1)) {
                        u16* base = ws + H0OFF + wpar * HPAR + cg * 1024 + actrow * 8;
                        __hip_atomic_store((unsigned int*)(base + acthc), pa, __ATOMIC_RELAXED, __HIP_MEMORY_SCOPE_AGENT);
                    }
                }
            }
        }

        barrier_arrive(flags, tid, bid, p + 2);
        if (lyr == 0 && p + 1 < Tt) accx = xgemm(p + 1);
        barrier_wait(flags, tid, p + 2);
    }

    // ---- final logits: h1(T-1) lives in parity 1 (frag-major addressing, unchanged) ----
    if (bid == 0 && tid < 256) {
        int b = tid >> 1, jj = tid & 1;
        float sum = bd[jj];
        const u16* hh = ws + H1OFF + 1 * HPAR;
        for (int g = 0; g < 64; g++) {
#pragma unroll
            for (int j4 = 0; j4 < 8; j4 += 4) {
                ull u = __hip_atomic_load((const ull*)(hh + (g * 128 + b) * 8 + j4),
                                          __ATOMIC_RELAXED, __HIP_MEMORY_SCOPE_AGENT);
#pragma unroll
                for (int e = 0; e < 4; e++)
                    sum += bits_f((u16)(u >> (16 * e))) * Wd[(g * 8 + j4 + e) * 2 + jj];
            }
        }
        out[b * 2 + jj] = sum;
    }
}

extern "C" void kernel_launch(void* const* d_in, const int* in_sizes, int n_in,
                              void* d_out, int out_size, void* d_ws, size_t ws_size,
                              hipStream_t stream) {
    const int*   x   = (const int*)d_in[0];
    const float* emb = (const float*)d_in[1];
    const float* W0  = (const float*)d_in[2];
    const float* b0  = (const float*)d_in[3];
    const float* W1  = (const float*)d_in[4];
    const float* b1  = (const float*)d_in[5];
    const float* Wd  = (const float*)d_in[6];
    const float* bd  = (const float*)d_in[7];
    float* out = (float*)d_out;
    u16* ws = (u16*)d_ws;

    void* args[] = { (void*)&x, (void*)&emb, (void*)&W0, (void*)&b0, (void*)&W1,
                     (void*)&b1, (void*)&Wd, (void*)&bd, (void*)&out, (void*)&ws };
    hipLaunchCooperativeKernel((void*)lstm_coop, dim3(256), dim3(1024), args, 0, stream);
}